// Round 8
// baseline (1022.749 us; speedup 1.0000x reference)
//
#include <hip/hip_runtime.h>
#include <math.h>

typedef short  bf16x8 __attribute__((ext_vector_type(8)));
typedef float  f32x4  __attribute__((ext_vector_type(4)));

#define DIM   1024
#define RANK  256
#define NROWS 16
#define NT    1024
#define NWAVE 16
#define TOTAL_ROWS 4096
#define OUT_HALF (TOTAL_ROWS*DIM)

// LDS byte layout
#define VS_OFF   0            // ushort[16][1024], XOR-swizzled rows (32768)
#define H2_OFF   32768        // ushort[16][256],  XOR-swizzled rows (8192)
#define GS_OFF   40960        // ushort[16][1032]  pitch 2064 B (33024)
#define GS_PITCH 2064
#define WS_OFF   73984        // float[16][16] (1024)
#define SG_OFF   75008        // float[16]     (64)
// pad to 86016 so 2 blocks can never co-reside on a CU (2x86016 > 163840):
// guarantees 1 block/CU with grid == 256 CUs.
#define SMEM_BYTES 86016

static constexpr double XI  = 0.1786178958448091;
static constexpr double LAM = -0.2123418310626054;
static constexpr double CHI = -0.0662645826698185;

__device__ __forceinline__ unsigned short f2bf(float f) {
    unsigned u = __builtin_bit_cast(unsigned, f);
    u += 0x7FFFu + ((u >> 16) & 1u);        // round-to-nearest-even
    return (unsigned short)(u >> 16);
}
__device__ __forceinline__ float bf2f(unsigned short b) {
    return __builtin_bit_cast(float, ((unsigned)b) << 16);
}

// swizzle: byte ^= (row&7)<<4 -> 16 A-rows spread over 8 16B slots
__device__ __forceinline__ int vs_addr(int m, int kb) {
    return VS_OFF + ((m * 2048 + kb) ^ ((m & 7) << 4));
}
__device__ __forceinline__ int h2_addr(int m, int kb) {
    return H2_OFF + ((m * 512 + kb) ^ ((m & 7) << 4));
}

// ---- prep: pack U,W (fp32) into bf16 MFMA B-fragment order in d_ws ----
// B-frag 16x16x32: lane l holds B[k = kt*32 + (l>>4)*8 + j][n = nt*16 + (l&15)]
// U slot = kt*16+nt (kt<32,nt<16); W slot = 512 + kt*64+nt (kt<8,nt<64)
__global__ __launch_bounds__(256)
void prep_pack(const float* __restrict__ U, const float* __restrict__ Wm,
               bf16x8* __restrict__ pk)
{
    const int tid  = blockIdx.x * 256 + threadIdx.x;   // 0..65535
    const int lane = tid & 63;
    const int frag = tid >> 6;                          // 0..1023
    bf16x8 o;
    if (frag < 512) {
        const int kt = frag >> 4, nt = frag & 15;
        const int krow = kt * 32 + (lane >> 4) * 8;
        const int n    = nt * 16 + (lane & 15);
        #pragma unroll
        for (int j = 0; j < 8; ++j) o[j] = (short)f2bf(U[(krow + j) * RANK + n]);
    } else {
        const int f = frag - 512;
        const int kt = f >> 6, nt = f & 63;
        const int krow = kt * 32 + (lane >> 4) * 8;
        const int n    = nt * 16 + (lane & 15);
        #pragma unroll
        for (int j = 0; j < 8; ++j) o[j] = (short)f2bf(Wm[(krow + j) * DIM + n]);
    }
    pk[frag * 64 + lane] = o;
}

// 16 waves/block, 1 block/CU. waves_per_eu(4,4): min=max=4 -> VGPR cap 128
// AND the allocator cannot spill to chase 8 waves/EU (R5's failure).
// Demand is engineered to ~104 < 128: state 33 regs (no fr - force re-read
// in kick), H ring 44, G ring 56.
__global__ __launch_bounds__(NT)
__attribute__((amdgpu_waves_per_eu(4, 4)))
void omelyan_mfma(const float* __restrict__ x_in,
                  const float* __restrict__ v_in,
                  const float* __restrict__ force,
                  const float* __restrict__ Vw,
                  const int* __restrict__ steps_p,
                  const bf16x8* __restrict__ pk,
                  float* __restrict__ out)
{
    extern __shared__ char smem[];
    float* wsums = (float*)(smem + WS_OFF);
    float* sings = (float*)(smem + SG_OFF);

    const int t    = threadIdx.x;        // 0..1023
    const int lane = t & 63;
    const int w    = t >> 6;             // 0..15
    const int row0 = blockIdx.x * NROWS;
    const int nsteps = steps_p[0];

    const float dt = 0.01f;

    // per-thread elementwise state: element (m, d = t). NO force copy.
    float xr[NROWS], vr[NROWS];
    const float vw = Vw[t];

    #pragma unroll
    for (int m = 0; m < NROWS; ++m) {
        const int base = (row0 + m) * DIM + t;
        xr[m] = x_in[base];
        vr[m] = v_in[base];
        *(unsigned short*)(smem + vs_addr(m, 2 * t)) = f2bf(vr[m]);
    }
    __syncthreads();

    #pragma unroll 1
    for (int step = 0; step < nsteps; ++step) {
        #pragma unroll 1
        for (int sub = 0; sub < 4; ++sub) {
            const float cdt = dt * (sub == 0 ? (float)XI :
                                    sub == 1 ? (float)CHI :
                                    sub == 2 ? (float)(1.0 - 2.0 * (CHI + XI)) :
                                               (float)CHI);
            const float ddt = dt * ((sub == 0 || sub == 3)
                                    ? (float)((1.0 - 2.0 * LAM) * 0.5)
                                    : (float)LAM);

            // ---- drift x + r2 partial (barrier folded into b2) ----
            #pragma unroll
            for (int m = 0; m < NROWS; ++m) {
                xr[m] = fmaf(cdt, vr[m], xr[m]);
                float s = xr[m] * xr[m];
                #pragma unroll
                for (int off = 32; off >= 1; off >>= 1) s += __shfl_xor(s, off, 64);
                if (lane == 0) wsums[m * NWAVE + w] = s;
            }

            // ---- H: h = v @ U (M=16,N=256,K=1024); wave owns n-tile w ----
            {
                f32x4 hacc = {0.f, 0.f, 0.f, 0.f};
                bf16x8 bb[8];                           // ring-8 (8 KB in flight)
                #pragma unroll
                for (int s = 0; s < 8; ++s)
                    bb[s] = pk[(s * 16 + w) * 64 + lane];
                bf16x8 areg[2];
                areg[0] = *(const bf16x8*)(smem + vs_addr(lane & 15, (lane >> 4) * 16));
                #pragma unroll
                for (int ks = 0; ks < 32; ++ks) {
                    if (ks + 1 < 32)
                        areg[(ks + 1) & 1] = *(const bf16x8*)(smem + vs_addr(lane & 15, (ks + 1) * 64 + (lane >> 4) * 16));
                    hacc = __builtin_amdgcn_mfma_f32_16x16x32_bf16(areg[ks & 1], bb[ks & 7], hacc, 0, 0, 0);
                    if (ks + 8 < 32)
                        bb[ks & 7] = pk[((ks + 8) * 16 + w) * 64 + lane];
                }
                // h2 = (h*h) bf16, swizzled; D: col=lane&15, row=(lane>>4)*4+r
                #pragma unroll
                for (int r = 0; r < 4; ++r) {
                    const int m = (lane >> 4) * 4 + r;
                    const int n = w * 16 + (lane & 15);
                    *(unsigned short*)(smem + h2_addr(m, 2 * n)) = f2bf(hacc[r] * hacc[r]);
                }
            }
            __syncthreads();                            // b2 (covers wsums + h2)

            if (t < NROWS) {
                float r2 = 0.f;
                #pragma unroll
                for (int q = 0; q < NWAVE; ++q) r2 += wsums[t * NWAVE + q];
                sings[t] = 1.f + exp2f(-r2 * 1.4426950408889634f);
            }

            // ---- G: gamma = h2 @ W (M=16,N=1024,K=256); wave owns 4 n-tiles ----
            {
                f32x4 g0 = {0.f,0.f,0.f,0.f}, g1 = {0.f,0.f,0.f,0.f};
                f32x4 g2 = {0.f,0.f,0.f,0.f}, g3 = {0.f,0.f,0.f,0.f};
                bf16x8 wb[8];                           // flat ring-8 over u (2 kk ahead)
                #pragma unroll
                for (int u = 0; u < 8; ++u) {
                    const int kk = u >> 2, i = u & 3;
                    wb[u] = pk[(512 + kk * 64 + w * 4 + i) * 64 + lane];
                }
                bf16x8 areg[2];
                areg[0] = *(const bf16x8*)(smem + h2_addr(lane & 15, (lane >> 4) * 16));
                #pragma unroll
                for (int kk = 0; kk < 8; ++kk) {
                    if (kk + 1 < 8)
                        areg[(kk + 1) & 1] = *(const bf16x8*)(smem + h2_addr(lane & 15, (kk + 1) * 64 + (lane >> 4) * 16));
                    g0 = __builtin_amdgcn_mfma_f32_16x16x32_bf16(areg[kk & 1], wb[(4*kk + 0) & 7], g0, 0, 0, 0);
                    g1 = __builtin_amdgcn_mfma_f32_16x16x32_bf16(areg[kk & 1], wb[(4*kk + 1) & 7], g1, 0, 0, 0);
                    g2 = __builtin_amdgcn_mfma_f32_16x16x32_bf16(areg[kk & 1], wb[(4*kk + 2) & 7], g2, 0, 0, 0);
                    g3 = __builtin_amdgcn_mfma_f32_16x16x32_bf16(areg[kk & 1], wb[(4*kk + 3) & 7], g3, 0, 0, 0);
                    if (kk + 2 < 8) {
                        #pragma unroll
                        for (int i = 0; i < 4; ++i)
                            wb[(4*kk + i) & 7] = pk[(512 + (kk + 2) * 64 + w * 4 + i) * 64 + lane];
                    }
                }
                // gs (bf16): col = (w*4+i)*16 + (lane&15), row = (lane>>4)*4+r
                #pragma unroll
                for (int r = 0; r < 4; ++r) {
                    const int m  = (lane >> 4) * 4 + r;
                    const int cb = (w * 4) * 16 + (lane & 15);
                    *(unsigned short*)(smem + GS_OFF + m * GS_PITCH + (cb +  0) * 2) = f2bf(g0[r]);
                    *(unsigned short*)(smem + GS_OFF + m * GS_PITCH + (cb + 16) * 2) = f2bf(g1[r]);
                    *(unsigned short*)(smem + GS_OFF + m * GS_PITCH + (cb + 32) * 2) = f2bf(g2[r]);
                    *(unsigned short*)(smem + GS_OFF + m * GS_PITCH + (cb + 48) * 2) = f2bf(g3[r]);
                }
            }
            __syncthreads();                            // b3 (covers gs + sings)

            // ---- kick: v += ddt*(force - gamma*gate*sing); refresh vs ----
            // force re-read from global (L2-resident): saves 16 VGPRs of state
            #pragma unroll
            for (int m = 0; m < NROWS; ++m) {
                const float fm = force[(row0 + m) * DIM + t];
                const float gmm = bf2f(*(const unsigned short*)(smem + GS_OFF + m * GS_PITCH + 2 * t));
                const float sing = sings[m];
                const float z  = xr[m] * vw;
                const float e  = exp2f(z * 2.885390081777927f);   // e^(2z)
                const float th = 1.f - 2.f / (e + 1.f);           // tanh(z)
                const float gate = fmaf(0.1f, th, 1.f);
                const float a = fm - gmm * gate * sing;
                vr[m] = fmaf(ddt, a, vr[m]);
                *(unsigned short*)(smem + vs_addr(m, 2 * t)) = f2bf(vr[m]);
            }
            __syncthreads();                            // b4 (vs ready for next H)
        } // sub

        // final drift: x += C5*dt*v
        const float c5dt = dt * (float)XI;
        #pragma unroll
        for (int m = 0; m < NROWS; ++m)
            xr[m] = fmaf(c5dt, vr[m], xr[m]);
    } // step

    // ---- store (x, v) ----
    #pragma unroll
    for (int m = 0; m < NROWS; ++m) {
        const int base = (row0 + m) * DIM + t;
        out[base] = xr[m];
        out[OUT_HALF + base] = vr[m];
    }
}

extern "C" void kernel_launch(void* const* d_in, const int* in_sizes, int n_in,
                              void* d_out, int out_size, void* d_ws, size_t ws_size,
                              hipStream_t stream) {
    const float* x_in  = (const float*)d_in[0];
    const float* v_in  = (const float*)d_in[1];
    const float* force = (const float*)d_in[2];
    const float* Umat  = (const float*)d_in[3];
    const float* Wmat  = (const float*)d_in[4];
    const float* Vw    = (const float*)d_in[5];
    const int*   steps = (const int*)d_in[6];
    float* out = (float*)d_out;
    bf16x8* pk = (bf16x8*)d_ws;   // 1 MiB

    (void)hipFuncSetAttribute((const void*)omelyan_mfma,
                              hipFuncAttributeMaxDynamicSharedMemorySize,
                              SMEM_BYTES);

    prep_pack<<<dim3(256), dim3(256), 0, stream>>>(Umat, Wmat, pk);
    omelyan_mfma<<<dim3(TOTAL_ROWS / NROWS), dim3(NT), SMEM_BYTES, stream>>>(
        x_in, v_in, force, Vw, steps, pk, out);
}